// Round 1
// baseline (576.840 us; speedup 1.0000x reference)
//
#include <hip/hip_runtime.h>
#include <math.h>

#define N_DIN 256      // D_IN
#define N_COUT 256     // H*D_OUT
#define NHEAD 4
#define DHEAD 64
#define NEG_SLOPE 0.2f

// ---------------- projection GEMM: out[n][c] = sum_k feat[n][k]*W[c][k] + b[c]
#define BM 64
#define BN 64
#define BK 32

__global__ __launch_bounds__(256) void proj_gemm(
    const float* __restrict__ feat,
    const float* __restrict__ Wsrc, const float* __restrict__ bsrc,
    const float* __restrict__ Wdst, const float* __restrict__ bdst,
    float* __restrict__ fsrc, float* __restrict__ fdst, int n)
{
    __shared__ float As[BK][BM + 4];   // As[k][m], padded for bank spread + 16B align
    __shared__ float Bs[BK][BN + 4];   // Bs[k][c]

    const int bm = blockIdx.x;
    const int cb = blockIdx.y;              // 0..7 ; 0..3 -> src cols, 4..7 -> dst cols
    const bool is_src = cb < 4;
    const int col0 = (cb & 3) * BN;
    const float* __restrict__ W    = is_src ? Wsrc : Wdst;
    const float* __restrict__ bias = is_src ? bsrc : bdst;
    float* __restrict__ outp       = is_src ? fsrc : fdst;

    const int row0 = bm * BM;
    const int t = threadIdx.x;
    const int tx = t & 15, ty = t >> 4;     // 16 x 16 thread tile, 4x4 micro

    float acc[4][4] = {};

    for (int k0 = 0; k0 < N_DIN; k0 += BK) {
        // load A tile: 64 rows x 32 k = 512 float4, 2 per thread
        int idx = t;
        #pragma unroll
        for (int r = 0; r < 2; ++r, idx += 256) {
            int m  = idx >> 3;
            int kq = idx & 7;
            int row = row0 + m;
            float4 v = make_float4(0.f, 0.f, 0.f, 0.f);
            if (row < n)
                v = *reinterpret_cast<const float4*>(&feat[row * N_DIN + k0 + kq * 4]);
            As[kq * 4 + 0][m] = v.x; As[kq * 4 + 1][m] = v.y;
            As[kq * 4 + 2][m] = v.z; As[kq * 4 + 3][m] = v.w;
        }
        // load B tile: 64 cols x 32 k
        idx = t;
        #pragma unroll
        for (int r = 0; r < 2; ++r, idx += 256) {
            int c  = idx >> 3;
            int kq = idx & 7;
            float4 v = *reinterpret_cast<const float4*>(&W[(col0 + c) * N_DIN + k0 + kq * 4]);
            Bs[kq * 4 + 0][c] = v.x; Bs[kq * 4 + 1][c] = v.y;
            Bs[kq * 4 + 2][c] = v.z; Bs[kq * 4 + 3][c] = v.w;
        }
        __syncthreads();
        #pragma unroll
        for (int kk = 0; kk < BK; ++kk) {
            float a[4], b[4];
            *reinterpret_cast<float4*>(a) = *reinterpret_cast<const float4*>(&As[kk][ty * 4]);
            *reinterpret_cast<float4*>(b) = *reinterpret_cast<const float4*>(&Bs[kk][tx * 4]);
            #pragma unroll
            for (int i = 0; i < 4; ++i)
                #pragma unroll
                for (int j = 0; j < 4; ++j)
                    acc[i][j] += a[i] * b[j];
        }
        __syncthreads();
    }

    // epilogue: +bias, float4 stores
    #pragma unroll
    for (int i = 0; i < 4; ++i) {
        int row = row0 + ty * 4 + i;
        if (row >= n) continue;
        int c0 = col0 + tx * 4;
        float4 v = make_float4(acc[i][0] + bias[c0 + 0],
                               acc[i][1] + bias[c0 + 1],
                               acc[i][2] + bias[c0 + 2],
                               acc[i][3] + bias[c0 + 3]);
        *reinterpret_cast<float4*>(&outp[row * N_COUT + c0]) = v;
    }
}

// ---------------- CSR build ----------------
__global__ void zero_ints(int* __restrict__ p, int n)
{
    int i = blockIdx.x * 256 + threadIdx.x;
    if (i < n) p[i] = 0;
}

__global__ void count_deg(const int* __restrict__ dst, int* __restrict__ deg, int E)
{
    int i = blockIdx.x * 256 + threadIdx.x;
    if (i < E) atomicAdd(&deg[dst[i]], 1);
}

// single-block exclusive scan of deg[0..n) -> offsets[0..n], cursor[0..n)
__global__ __launch_bounds__(1024) void scan_kernel(
    const int* __restrict__ deg, int* __restrict__ offsets, int* __restrict__ cursor, int n)
{
    __shared__ int wsum[16];
    __shared__ int chunk_base;
    const int t = threadIdx.x;
    const int lane = t & 63, wv = t >> 6;
    if (t == 0) chunk_base = 0;
    __syncthreads();

    for (int start = 0; start < n; start += 1024) {
        int i = start + t;
        int v = (i < n) ? deg[i] : 0;
        int x = v;
        #pragma unroll
        for (int o = 1; o < 64; o <<= 1) {
            int y = __shfl_up(x, (unsigned)o);
            if (lane >= o) x += y;
        }
        if (lane == 63) wsum[wv] = x;
        __syncthreads();
        if (wv == 0 && lane < 16) {
            int s = wsum[lane];
            #pragma unroll
            for (int o = 1; o < 16; o <<= 1) {
                int y = __shfl_up(s, (unsigned)o);
                if (lane >= o) s += y;
            }
            wsum[lane] = s;   // inclusive scan of wave sums
        }
        __syncthreads();
        int wbase = (wv == 0) ? 0 : wsum[wv - 1];
        int excl = chunk_base + wbase + x - v;
        if (i < n) { offsets[i] = excl; cursor[i] = excl; }
        int total = chunk_base + wsum[15];
        __syncthreads();
        if (t == 0) chunk_base = total;
        __syncthreads();
    }
    if (t == 0) offsets[n] = chunk_base;
}

__global__ void scatter_edges(const int* __restrict__ src, const int* __restrict__ dst,
                              int* __restrict__ cursor, int* __restrict__ ssrc, int E)
{
    int i = blockIdx.x * 256 + threadIdx.x;
    if (i < E) {
        int d = dst[i];
        int pos = atomicAdd(&cursor[d], 1);
        ssrc[pos] = src[i];
    }
}

// ---------------- fused per-dst-node pass: score + online softmax + weighted sum
// block = 256 threads = 4 waves; wave w = head w; lane = dim within head
__global__ __launch_bounds__(256) void gat_node(
    const float* __restrict__ fsrc, const float* __restrict__ fdst,
    const float* __restrict__ attn, const int* __restrict__ offsets,
    const int* __restrict__ ssrc, float* __restrict__ out, int n)
{
    const int v = blockIdx.x;
    const int t = threadIdx.x;
    const int c = t;                 // h*64 + lane, t already spans [0,256)
    const int lane = t & 63;
    (void)lane;

    const float fd = fdst[v * N_COUT + c];
    const float aw = attn[c];
    const int beg = offsets[v];
    const int end = offsets[v + 1];

    float m = -INFINITY, l = 0.f, acc = 0.f;
    for (int j = beg; j < end; ++j) {
        int u = ssrc[j];
        float fs = fsrc[u * N_COUT + c];
        float x = fs + fd;
        float e = (x > 0.f) ? x : NEG_SLOPE * x;
        float s = e * aw;
        #pragma unroll
        for (int o = 32; o; o >>= 1) s += __shfl_xor(s, o);
        float mnew = fmaxf(m, s);
        float scale = __expf(m - mnew);
        float p = __expf(s - mnew);
        l = l * scale + p;
        acc = acc * scale + p * fs;
        m = mnew;
    }
    out[v * N_COUT + c] = (l > 0.f) ? (acc / l) : 0.f;
}

// ---------------- launch ----------------
extern "C" void kernel_launch(void* const* d_in, const int* in_sizes, int n_in,
                              void* d_out, int out_size, void* d_ws, size_t ws_size,
                              hipStream_t stream)
{
    const float* feat = (const float*)d_in[0];
    const int*   src  = (const int*)d_in[1];
    const int*   dst  = (const int*)d_in[2];
    const float* Wsrc = (const float*)d_in[3];
    const float* bsrc = (const float*)d_in[4];
    const float* Wdst = (const float*)d_in[5];
    const float* bdst = (const float*)d_in[6];
    const float* attn = (const float*)d_in[7];

    const int N = in_sizes[0] / N_DIN;     // 50000
    const int E = in_sizes[1];             // 800000
    float* out = (float*)d_out;

    // workspace layout
    char* ws = (char*)d_ws;
    float* fsrc    = (float*)ws;                    ws += (size_t)N * N_COUT * sizeof(float);
    float* fdst    = (float*)ws;                    ws += (size_t)N * N_COUT * sizeof(float);
    int*   offsets = (int*)ws;                      ws += (size_t)(N + 1) * sizeof(int);
    int*   cursor  = (int*)ws;                      ws += (size_t)N * sizeof(int);
    int*   ssrc    = (int*)ws;                      ws += (size_t)E * sizeof(int);

    // 1) projections
    dim3 ggrid((N + BM - 1) / BM, 8);
    proj_gemm<<<ggrid, 256, 0, stream>>>(feat, Wsrc, bsrc, Wdst, bdst, fsrc, fdst, N);

    // 2) CSR by dst
    zero_ints<<<(N + 255) / 256, 256, 0, stream>>>(cursor, N);
    count_deg<<<(E + 255) / 256, 256, 0, stream>>>(dst, cursor, E);
    scan_kernel<<<1, 1024, 0, stream>>>(cursor, offsets, cursor, N);
    scatter_edges<<<(E + 255) / 256, 256, 0, stream>>>(src, dst, cursor, ssrc, E);

    // 3) fused edge softmax + aggregation
    gat_node<<<N, 256, 0, stream>>>(fsrc, fdst, attn, offsets, ssrc, out, N);
}

// Round 2
// 344.787 us; speedup vs baseline: 1.6730x; 1.6730x over previous
//
#include <hip/hip_runtime.h>
#include <hip/hip_bf16.h>
#include <math.h>

#define N_DIN 256      // D_IN
#define N_COUT 256     // H*D_OUT
#define NEG_SLOPE 0.2f

typedef short s16x8 __attribute__((ext_vector_type(8)));
typedef float f32x4 __attribute__((ext_vector_type(4)));

__device__ __forceinline__ float bf2f(unsigned short u) {
    return __uint_as_float(((unsigned int)u) << 16);
}
__device__ __forceinline__ unsigned short f2bf(float f) {
    __hip_bfloat16 h = __float2bfloat16(f);
    return *reinterpret_cast<unsigned short*>(&h);
}

// ---------------- fp32 -> bf16 conversion for feat, Wsrc, Wdst ----------------
// grid: [0,6250) feat (12.8M elems), [6250,6282) Wsrc (65536), [6282,6314) Wdst
__global__ __launch_bounds__(256) void convert_all(
    const float* __restrict__ feat, const float* __restrict__ Wsrc,
    const float* __restrict__ Wdst, unsigned short* __restrict__ feat_bf,
    unsigned short* __restrict__ wsrc_bf, unsigned short* __restrict__ wdst_bf)
{
    const int b = blockIdx.x;
    const float* __restrict__ in;
    unsigned short* __restrict__ out;
    size_t base;
    if (b < 6250)      { in = feat; out = feat_bf; base = (size_t)b * 2048; }
    else if (b < 6282) { in = Wsrc; out = wsrc_bf; base = (size_t)(b - 6250) * 2048; }
    else               { in = Wdst; out = wdst_bf; base = (size_t)(b - 6282) * 2048; }
    size_t i = base + (size_t)threadIdx.x * 8;
    float4 v0 = *reinterpret_cast<const float4*>(&in[i]);
    float4 v1 = *reinterpret_cast<const float4*>(&in[i + 4]);
    ushort4 o0 = make_ushort4(f2bf(v0.x), f2bf(v0.y), f2bf(v0.z), f2bf(v0.w));
    ushort4 o1 = make_ushort4(f2bf(v1.x), f2bf(v1.y), f2bf(v1.z), f2bf(v1.w));
    *reinterpret_cast<ushort4*>(&out[i]) = o0;
    *reinterpret_cast<ushort4*>(&out[i + 4]) = o1;
}

// ---------------- bf16 MFMA projection: out[n][c] = feat @ W^T + b ----------------
// grid.x = M-tiles of 128, grid.y: 0..1 -> src col-tiles, 2..3 -> dst col-tiles
// block = 256 = 4 waves in 2x2; each wave computes 64x64 via 4x4 frags of 16x16x32
__global__ __launch_bounds__(256) void proj_mfma(
    const unsigned short* __restrict__ feat_bf,
    const unsigned short* __restrict__ wsrc_bf, const float* __restrict__ bsrc,
    const unsigned short* __restrict__ wdst_bf, const float* __restrict__ bdst,
    unsigned short* __restrict__ fsrc_bf, unsigned short* __restrict__ fdst_bf, int n)
{
    const int t = threadIdx.x;
    const int lane = t & 63;
    const int wid = t >> 6;
    const int wr = wid >> 1, wc = wid & 1;
    const int y = blockIdx.y;
    const unsigned short* __restrict__ W = (y < 2) ? wsrc_bf : wdst_bf;
    const float* __restrict__ bias       = (y < 2) ? bsrc : bdst;
    unsigned short* __restrict__ outp    = (y < 2) ? fsrc_bf : fdst_bf;
    const int col0 = (y & 1) * 128 + wc * 64;
    const int row0 = blockIdx.x * 128 + wr * 64;

    const int lr = lane & 15;    // A: row-in-frag; B: col-in-frag; D: col-in-frag
    const int kc = lane >> 4;    // k-chunk (8 bf16 each)

    int arow[4];
    #pragma unroll
    for (int m = 0; m < 4; ++m) {
        int r = row0 + m * 16 + lr;
        arow[m] = (r < n) ? r : (n - 1);   // clamp; invalid rows masked at store
    }

    f32x4 acc[4][4] = {};

    #pragma unroll
    for (int k0 = 0; k0 < N_DIN; k0 += 32) {
        s16x8 a[4], b[4];
        #pragma unroll
        for (int m = 0; m < 4; ++m)
            a[m] = *reinterpret_cast<const s16x8*>(
                &feat_bf[(size_t)arow[m] * N_DIN + k0 + kc * 8]);
        #pragma unroll
        for (int nf = 0; nf < 4; ++nf)
            b[nf] = *reinterpret_cast<const s16x8*>(
                &W[(size_t)(col0 + nf * 16 + lr) * N_DIN + k0 + kc * 8]);
        #pragma unroll
        for (int m = 0; m < 4; ++m)
            #pragma unroll
            for (int nf = 0; nf < 4; ++nf)
                acc[m][nf] = __builtin_amdgcn_mfma_f32_16x16x32_bf16(
                    a[m], b[nf], acc[m][nf], 0, 0, 0);
    }

    // epilogue: D lane mapping col=lane&15, row=(lane>>4)*4+r
    #pragma unroll
    for (int nf = 0; nf < 4; ++nf) {
        const int col = col0 + nf * 16 + lr;
        const float bv = bias[col];
        #pragma unroll
        for (int m = 0; m < 4; ++m) {
            #pragma unroll
            for (int r = 0; r < 4; ++r) {
                int row = row0 + m * 16 + (lane >> 4) * 4 + r;
                if (row < n)
                    outp[(size_t)row * N_COUT + col] = f2bf(acc[m][nf][r] + bv);
            }
        }
    }
}

// ---------------- CSR build ----------------
__global__ void zero_ints(int* __restrict__ p, int n)
{
    int i = blockIdx.x * 256 + threadIdx.x;
    if (i < n) p[i] = 0;
}

__global__ void count_deg(const int* __restrict__ dst, int* __restrict__ deg, int E)
{
    int i = blockIdx.x * 256 + threadIdx.x;
    if (i < E) atomicAdd(&deg[dst[i]], 1);
}

__global__ __launch_bounds__(1024) void scan_kernel(
    const int* __restrict__ deg, int* __restrict__ offsets, int* __restrict__ cursor, int n)
{
    __shared__ int wsum[16];
    __shared__ int chunk_base;
    const int t = threadIdx.x;
    const int lane = t & 63, wv = t >> 6;
    if (t == 0) chunk_base = 0;
    __syncthreads();

    for (int start = 0; start < n; start += 1024) {
        int i = start + t;
        int v = (i < n) ? deg[i] : 0;
        int x = v;
        #pragma unroll
        for (int o = 1; o < 64; o <<= 1) {
            int y = __shfl_up(x, (unsigned)o);
            if (lane >= o) x += y;
        }
        if (lane == 63) wsum[wv] = x;
        __syncthreads();
        if (wv == 0 && lane < 16) {
            int s = wsum[lane];
            #pragma unroll
            for (int o = 1; o < 16; o <<= 1) {
                int y = __shfl_up(s, (unsigned)o);
                if (lane >= o) s += y;
            }
            wsum[lane] = s;
        }
        __syncthreads();
        int wbase = (wv == 0) ? 0 : wsum[wv - 1];
        int excl = chunk_base + wbase + x - v;
        if (i < n) { offsets[i] = excl; cursor[i] = excl; }
        int total = chunk_base + wsum[15];
        __syncthreads();
        if (t == 0) chunk_base = total;
        __syncthreads();
    }
    if (t == 0) offsets[n] = chunk_base;
}

__global__ void scatter_edges(const int* __restrict__ src, const int* __restrict__ dst,
                              int* __restrict__ cursor, int* __restrict__ ssrc, int E)
{
    int i = blockIdx.x * 256 + threadIdx.x;
    if (i < E) {
        int d = dst[i];
        int pos = atomicAdd(&cursor[d], 1);
        ssrc[pos] = src[i];
    }
}

// ---------------- fused per-dst-node pass: wave-per-node, bf16 gathers ----------------
// wave handles one node; lane owns dims [lane*4, lane*4+4) (head = lane>>4);
// head-dot reduce = 4 shuffles over the 16-lane head group
__global__ __launch_bounds__(256) void gat_node2(
    const unsigned short* __restrict__ fsrc_bf, const unsigned short* __restrict__ fdst_bf,
    const float* __restrict__ attn, const int* __restrict__ offsets,
    const int* __restrict__ ssrc, float* __restrict__ out, int n)
{
    const int v = blockIdx.x * 4 + (threadIdx.x >> 6);
    if (v >= n) return;
    const int lane = threadIdx.x & 63;
    const int cb = lane * 4;

    ushort4 fdr = *reinterpret_cast<const ushort4*>(&fdst_bf[(size_t)v * N_COUT + cb]);
    const float fd0 = bf2f(fdr.x), fd1 = bf2f(fdr.y), fd2 = bf2f(fdr.z), fd3 = bf2f(fdr.w);
    const float4 aw = *reinterpret_cast<const float4*>(&attn[cb]);

    const int beg = offsets[v];
    const int end = offsets[v + 1];

    float m = -INFINITY, l = 0.f;
    float acc0 = 0.f, acc1 = 0.f, acc2 = 0.f, acc3 = 0.f;

    for (int j = beg; j < end; ++j) {
        int u = ssrc[j];
        ushort4 fr = *reinterpret_cast<const ushort4*>(&fsrc_bf[(size_t)u * N_COUT + cb]);
        float fs0 = bf2f(fr.x), fs1 = bf2f(fr.y), fs2 = bf2f(fr.z), fs3 = bf2f(fr.w);

        float x0 = fs0 + fd0, x1 = fs1 + fd1, x2 = fs2 + fd2, x3 = fs3 + fd3;
        float e0 = fmaxf(x0, 0.f) + NEG_SLOPE * fminf(x0, 0.f);
        float e1 = fmaxf(x1, 0.f) + NEG_SLOPE * fminf(x1, 0.f);
        float e2 = fmaxf(x2, 0.f) + NEG_SLOPE * fminf(x2, 0.f);
        float e3 = fmaxf(x3, 0.f) + NEG_SLOPE * fminf(x3, 0.f);
        float s = e0 * aw.x + e1 * aw.y + e2 * aw.z + e3 * aw.w;
        s += __shfl_xor(s, 1);
        s += __shfl_xor(s, 2);
        s += __shfl_xor(s, 4);
        s += __shfl_xor(s, 8);

        float mnew = fmaxf(m, s);
        float scale = __expf(m - mnew);
        float p = __expf(s - mnew);
        l = l * scale + p;
        acc0 = acc0 * scale + p * fs0;
        acc1 = acc1 * scale + p * fs1;
        acc2 = acc2 * scale + p * fs2;
        acc3 = acc3 * scale + p * fs3;
        m = mnew;
    }

    const float inv = (l > 0.f) ? (1.0f / l) : 0.f;
    float4 o = make_float4(acc0 * inv, acc1 * inv, acc2 * inv, acc3 * inv);
    *reinterpret_cast<float4*>(&out[(size_t)v * N_COUT + cb]) = o;
}

// ---------------- launch ----------------
extern "C" void kernel_launch(void* const* d_in, const int* in_sizes, int n_in,
                              void* d_out, int out_size, void* d_ws, size_t ws_size,
                              hipStream_t stream)
{
    const float* feat = (const float*)d_in[0];
    const int*   src  = (const int*)d_in[1];
    const int*   dst  = (const int*)d_in[2];
    const float* Wsrc = (const float*)d_in[3];
    const float* bsrc = (const float*)d_in[4];
    const float* Wdst = (const float*)d_in[5];
    const float* bdst = (const float*)d_in[6];
    const float* attn = (const float*)d_in[7];

    const int N = in_sizes[0] / N_DIN;     // 50000
    const int E = in_sizes[1];             // 800000
    float* out = (float*)d_out;

    // workspace layout (all 16B-aligned)
    char* ws = (char*)d_ws;
    unsigned short* feat_bf = (unsigned short*)ws; ws += (size_t)N * N_DIN * sizeof(unsigned short);
    unsigned short* wsrc_bf = (unsigned short*)ws; ws += (size_t)N_COUT * N_DIN * sizeof(unsigned short);
    unsigned short* wdst_bf = (unsigned short*)ws; ws += (size_t)N_COUT * N_DIN * sizeof(unsigned short);
    unsigned short* fsrc_bf = (unsigned short*)ws; ws += (size_t)N * N_COUT * sizeof(unsigned short);
    unsigned short* fdst_bf = (unsigned short*)ws; ws += (size_t)N * N_COUT * sizeof(unsigned short);
    int* offsets = (int*)ws;  ws += (size_t)(N + 1) * sizeof(int);
    int* cursor  = (int*)ws;  ws += (size_t)N * sizeof(int);
    int* ssrc    = (int*)ws;  ws += (size_t)E * sizeof(int);

    // 1) convert feat/W to bf16
    convert_all<<<6314, 256, 0, stream>>>(feat, Wsrc, Wdst, feat_bf, wsrc_bf, wdst_bf);

    // 2) bf16 MFMA projections
    dim3 ggrid((N + 127) / 128, 4);
    proj_mfma<<<ggrid, 256, 0, stream>>>(feat_bf, wsrc_bf, bsrc, wdst_bf, bdst,
                                         fsrc_bf, fdst_bf, N);

    // 3) CSR by dst
    zero_ints<<<(N + 255) / 256, 256, 0, stream>>>(cursor, N);
    count_deg<<<(E + 255) / 256, 256, 0, stream>>>(dst, cursor, E);
    scan_kernel<<<1, 1024, 0, stream>>>(cursor, offsets, cursor, N);
    scatter_edges<<<(E + 255) / 256, 256, 0, stream>>>(src, dst, cursor, ssrc, E);

    // 4) fused edge softmax + aggregation
    gat_node2<<<(N + 3) / 4, 256, 0, stream>>>(fsrc_bf, fdst_bf, attn, offsets, ssrc, out, N);
}

// Round 3
// 308.643 us; speedup vs baseline: 1.8690x; 1.1171x over previous
//
#include <hip/hip_runtime.h>
#include <hip/hip_bf16.h>
#include <math.h>

#define N_DIN 256      // D_IN
#define N_COUT 256     // H*D_OUT
#define NEG_SLOPE 0.2f

typedef short s16x8 __attribute__((ext_vector_type(8)));
typedef float f32x4 __attribute__((ext_vector_type(4)));

__device__ __forceinline__ float bf2f(unsigned short u) {
    return __uint_as_float(((unsigned int)u) << 16);
}
__device__ __forceinline__ unsigned short f2bf(float f) {
    __hip_bfloat16 h = __float2bfloat16(f);
    return *reinterpret_cast<unsigned short*>(&h);
}

// ---------------- fp32 -> bf16 conversion for feat, Wsrc, Wdst ----------------
// grid: [0,6250) feat (12.8M elems), [6250,6282) Wsrc (65536), [6282,6314) Wdst
__global__ __launch_bounds__(256) void convert_all(
    const float* __restrict__ feat, const float* __restrict__ Wsrc,
    const float* __restrict__ Wdst, unsigned short* __restrict__ feat_bf,
    unsigned short* __restrict__ wsrc_bf, unsigned short* __restrict__ wdst_bf)
{
    const int b = blockIdx.x;
    const float* __restrict__ in;
    unsigned short* __restrict__ out;
    size_t base;
    if (b < 6250)      { in = feat; out = feat_bf; base = (size_t)b * 2048; }
    else if (b < 6282) { in = Wsrc; out = wsrc_bf; base = (size_t)(b - 6250) * 2048; }
    else               { in = Wdst; out = wdst_bf; base = (size_t)(b - 6282) * 2048; }
    size_t i = base + (size_t)threadIdx.x * 8;
    float4 v0 = *reinterpret_cast<const float4*>(&in[i]);
    float4 v1 = *reinterpret_cast<const float4*>(&in[i + 4]);
    ushort4 o0 = make_ushort4(f2bf(v0.x), f2bf(v0.y), f2bf(v0.z), f2bf(v0.w));
    ushort4 o1 = make_ushort4(f2bf(v1.x), f2bf(v1.y), f2bf(v1.z), f2bf(v1.w));
    *reinterpret_cast<ushort4*>(&out[i]) = o0;
    *reinterpret_cast<ushort4*>(&out[i + 4]) = o1;
}

// ---------------- bf16 MFMA projection ----------------
// One block = 8 waves = 512 threads handles a 64-row tile and ALL 512 virtual
// output cols ([fsrc 0..255 | fdst 0..255]); wave w owns cols (w&3)*64 of
// (w<4 ? src : dst). feat tile (32KB) is read once per block, L1-resident
// across the 8 waves. MFMA operands SWAPPED (A=W-frag, B=feat-frag) so the
// 4 consecutive acc regs = 4 consecutive output cols -> ushort4 stores.
__global__ __launch_bounds__(512) void proj_mfma(
    const unsigned short* __restrict__ feat_bf,
    const unsigned short* __restrict__ wsrc_bf, const float* __restrict__ bsrc,
    const unsigned short* __restrict__ wdst_bf, const float* __restrict__ bdst,
    unsigned short* __restrict__ fsrc_bf, unsigned short* __restrict__ fdst_bf, int n)
{
    const int t = threadIdx.x;
    const int lane = t & 63;
    const int w = t >> 6;
    const unsigned short* __restrict__ W = (w < 4) ? wsrc_bf : wdst_bf;
    const float* __restrict__ bias       = (w < 4) ? bsrc : bdst;
    unsigned short* __restrict__ outp    = (w < 4) ? fsrc_bf : fdst_bf;
    const int col0 = (w & 3) * 64;
    const int row0 = blockIdx.x * 64;

    const int lr = lane & 15;
    const int kc = lane >> 4;    // k-chunk (8 bf16 each)

    int brow[4];
    #pragma unroll
    for (int m = 0; m < 4; ++m) {
        int r = row0 + m * 16 + lr;
        brow[m] = (r < n) ? r : (n - 1);   // clamp; masked at store
    }

    f32x4 acc[4][4] = {};   // [nf][m]

    #pragma unroll
    for (int k0 = 0; k0 < N_DIN; k0 += 32) {
        s16x8 a[4], b[4];
        #pragma unroll
        for (int nf = 0; nf < 4; ++nf)
            a[nf] = *reinterpret_cast<const s16x8*>(
                &W[(size_t)(col0 + nf * 16 + lr) * N_DIN + k0 + kc * 8]);
        #pragma unroll
        for (int m = 0; m < 4; ++m)
            b[m] = *reinterpret_cast<const s16x8*>(
                &feat_bf[(size_t)brow[m] * N_DIN + k0 + kc * 8]);
        #pragma unroll
        for (int nf = 0; nf < 4; ++nf)
            #pragma unroll
            for (int m = 0; m < 4; ++m)
                acc[nf][m] = __builtin_amdgcn_mfma_f32_16x16x32_bf16(
                    a[nf], b[m], acc[nf][m], 0, 0, 0);
    }

    // D layout: col(lane&15) = B idx = feat row (output row);
    //           row((lane>>4)*4+r) = A idx = W row (output col) -> vectorizable
    #pragma unroll
    for (int nf = 0; nf < 4; ++nf) {
        const int cbase = col0 + nf * 16 + kc * 4;
        const float4 bv = *reinterpret_cast<const float4*>(&bias[cbase]);
        #pragma unroll
        for (int m = 0; m < 4; ++m) {
            const int row = row0 + m * 16 + lr;
            if (row < n) {
                ushort4 o = make_ushort4(f2bf(acc[nf][m][0] + bv.x),
                                         f2bf(acc[nf][m][1] + bv.y),
                                         f2bf(acc[nf][m][2] + bv.z),
                                         f2bf(acc[nf][m][3] + bv.w));
                *reinterpret_cast<ushort4*>(&outp[(size_t)row * N_COUT + cbase]) = o;
            }
        }
    }
}

// ---------------- CSR build ----------------
__global__ void zero_ints(int* __restrict__ p, int n)
{
    int i = blockIdx.x * 256 + threadIdx.x;
    if (i < n) p[i] = 0;
}

__global__ void count_deg(const int* __restrict__ dst, int* __restrict__ deg, int E)
{
    int i = blockIdx.x * 256 + threadIdx.x;
    if (i < E) atomicAdd(&deg[dst[i]], 1);
}

__global__ __launch_bounds__(1024) void scan_kernel(
    const int* __restrict__ deg, int* __restrict__ offsets, int* __restrict__ cursor, int n)
{
    __shared__ int wsum[16];
    __shared__ int chunk_base;
    const int t = threadIdx.x;
    const int lane = t & 63, wv = t >> 6;
    if (t == 0) chunk_base = 0;
    __syncthreads();

    for (int start = 0; start < n; start += 1024) {
        int i = start + t;
        int v = (i < n) ? deg[i] : 0;
        int x = v;
        #pragma unroll
        for (int o = 1; o < 64; o <<= 1) {
            int y = __shfl_up(x, (unsigned)o);
            if (lane >= o) x += y;
        }
        if (lane == 63) wsum[wv] = x;
        __syncthreads();
        if (wv == 0 && lane < 16) {
            int s = wsum[lane];
            #pragma unroll
            for (int o = 1; o < 16; o <<= 1) {
                int y = __shfl_up(s, (unsigned)o);
                if (lane >= o) s += y;
            }
            wsum[lane] = s;
        }
        __syncthreads();
        int wbase = (wv == 0) ? 0 : wsum[wv - 1];
        int excl = chunk_base + wbase + x - v;
        if (i < n) { offsets[i] = excl; cursor[i] = excl; }
        int total = chunk_base + wsum[15];
        __syncthreads();
        if (t == 0) chunk_base = total;
        __syncthreads();
    }
    if (t == 0) offsets[n] = chunk_base;
}

__global__ void scatter_edges(const int* __restrict__ src, const int* __restrict__ dst,
                              int* __restrict__ cursor, int* __restrict__ ssrc, int E)
{
    int i = blockIdx.x * 256 + threadIdx.x;
    if (i < E) {
        int d = dst[i];
        int pos = atomicAdd(&cursor[d], 1);
        ssrc[pos] = src[i];
    }
}

// ---------------- fused per-dst-node pass: wave-per-node, 2-edge unroll ----------------
// wave handles one node; lane owns dims [lane*4, lane*4+4); head = lane>>4.
// Two edges per iteration: independent gathers + dots (2x ILP on the serial
// online-softmax chain), single merged rescale (3 exp / 3 FMA-per-dim per pair).
__global__ __launch_bounds__(256) void gat_node2(
    const unsigned short* __restrict__ fsrc_bf, const unsigned short* __restrict__ fdst_bf,
    const float* __restrict__ attn, const int* __restrict__ offsets,
    const int* __restrict__ ssrc, float* __restrict__ out, int n)
{
    const int v = blockIdx.x * 4 + (threadIdx.x >> 6);
    if (v >= n) return;
    const int lane = threadIdx.x & 63;
    const int cb = lane * 4;

    ushort4 fdr = *reinterpret_cast<const ushort4*>(&fdst_bf[(size_t)v * N_COUT + cb]);
    const float fd0 = bf2f(fdr.x), fd1 = bf2f(fdr.y), fd2 = bf2f(fdr.z), fd3 = bf2f(fdr.w);
    const float4 aw = *reinterpret_cast<const float4*>(&attn[cb]);

    const int beg = offsets[v];
    const int end = offsets[v + 1];

    float m = -INFINITY, l = 0.f;
    float acc0 = 0.f, acc1 = 0.f, acc2 = 0.f, acc3 = 0.f;

    int j = beg;
    for (; j + 2 <= end; j += 2) {
        const int u0 = ssrc[j];
        const int u1 = ssrc[j + 1];
        ushort4 fa = *reinterpret_cast<const ushort4*>(&fsrc_bf[(size_t)u0 * N_COUT + cb]);
        ushort4 fb = *reinterpret_cast<const ushort4*>(&fsrc_bf[(size_t)u1 * N_COUT + cb]);
        float a0 = bf2f(fa.x), a1 = bf2f(fa.y), a2 = bf2f(fa.z), a3 = bf2f(fa.w);
        float b0 = bf2f(fb.x), b1 = bf2f(fb.y), b2 = bf2f(fb.z), b3 = bf2f(fb.w);

        float xa0 = a0 + fd0, xa1 = a1 + fd1, xa2 = a2 + fd2, xa3 = a3 + fd3;
        float xb0 = b0 + fd0, xb1 = b1 + fd1, xb2 = b2 + fd2, xb3 = b3 + fd3;
        float sa = (fmaxf(xa0, 0.f) + NEG_SLOPE * fminf(xa0, 0.f)) * aw.x
                 + (fmaxf(xa1, 0.f) + NEG_SLOPE * fminf(xa1, 0.f)) * aw.y
                 + (fmaxf(xa2, 0.f) + NEG_SLOPE * fminf(xa2, 0.f)) * aw.z
                 + (fmaxf(xa3, 0.f) + NEG_SLOPE * fminf(xa3, 0.f)) * aw.w;
        float sb = (fmaxf(xb0, 0.f) + NEG_SLOPE * fminf(xb0, 0.f)) * aw.x
                 + (fmaxf(xb1, 0.f) + NEG_SLOPE * fminf(xb1, 0.f)) * aw.y
                 + (fmaxf(xb2, 0.f) + NEG_SLOPE * fminf(xb2, 0.f)) * aw.z
                 + (fmaxf(xb3, 0.f) + NEG_SLOPE * fminf(xb3, 0.f)) * aw.w;
        sa += __shfl_xor(sa, 1);  sb += __shfl_xor(sb, 1);
        sa += __shfl_xor(sa, 2);  sb += __shfl_xor(sb, 2);
        sa += __shfl_xor(sa, 4);  sb += __shfl_xor(sb, 4);
        sa += __shfl_xor(sa, 8);  sb += __shfl_xor(sb, 8);

        float mnew = fmaxf(m, fmaxf(sa, sb));
        float scale = __expf(m - mnew);
        float pa = __expf(sa - mnew);
        float pb = __expf(sb - mnew);
        l = fmaf(l, scale, pa + pb);
        acc0 = fmaf(acc0, scale, fmaf(pa, a0, pb * b0));
        acc1 = fmaf(acc1, scale, fmaf(pa, a1, pb * b1));
        acc2 = fmaf(acc2, scale, fmaf(pa, a2, pb * b2));
        acc3 = fmaf(acc3, scale, fmaf(pa, a3, pb * b3));
        m = mnew;
    }
    if (j < end) {
        const int u0 = ssrc[j];
        ushort4 fa = *reinterpret_cast<const ushort4*>(&fsrc_bf[(size_t)u0 * N_COUT + cb]);
        float a0 = bf2f(fa.x), a1 = bf2f(fa.y), a2 = bf2f(fa.z), a3 = bf2f(fa.w);
        float xa0 = a0 + fd0, xa1 = a1 + fd1, xa2 = a2 + fd2, xa3 = a3 + fd3;
        float sa = (fmaxf(xa0, 0.f) + NEG_SLOPE * fminf(xa0, 0.f)) * aw.x
                 + (fmaxf(xa1, 0.f) + NEG_SLOPE * fminf(xa1, 0.f)) * aw.y
                 + (fmaxf(xa2, 0.f) + NEG_SLOPE * fminf(xa2, 0.f)) * aw.z
                 + (fmaxf(xa3, 0.f) + NEG_SLOPE * fminf(xa3, 0.f)) * aw.w;
        sa += __shfl_xor(sa, 1);
        sa += __shfl_xor(sa, 2);
        sa += __shfl_xor(sa, 4);
        sa += __shfl_xor(sa, 8);
        float mnew = fmaxf(m, sa);
        float scale = __expf(m - mnew);
        float pa = __expf(sa - mnew);
        l = fmaf(l, scale, pa);
        acc0 = fmaf(acc0, scale, pa * a0);
        acc1 = fmaf(acc1, scale, pa * a1);
        acc2 = fmaf(acc2, scale, pa * a2);
        acc3 = fmaf(acc3, scale, pa * a3);
        m = mnew;
    }

    const float inv = (l > 0.f) ? (1.0f / l) : 0.f;
    float4 o = make_float4(acc0 * inv, acc1 * inv, acc2 * inv, acc3 * inv);
    *reinterpret_cast<float4*>(&out[(size_t)v * N_COUT + cb]) = o;
}

// ---------------- launch ----------------
extern "C" void kernel_launch(void* const* d_in, const int* in_sizes, int n_in,
                              void* d_out, int out_size, void* d_ws, size_t ws_size,
                              hipStream_t stream)
{
    const float* feat = (const float*)d_in[0];
    const int*   src  = (const int*)d_in[1];
    const int*   dst  = (const int*)d_in[2];
    const float* Wsrc = (const float*)d_in[3];
    const float* bsrc = (const float*)d_in[4];
    const float* Wdst = (const float*)d_in[5];
    const float* bdst = (const float*)d_in[6];
    const float* attn = (const float*)d_in[7];

    const int N = in_sizes[0] / N_DIN;     // 50000
    const int E = in_sizes[1];             // 800000
    float* out = (float*)d_out;

    // workspace layout (all 16B-aligned)
    char* ws = (char*)d_ws;
    unsigned short* feat_bf = (unsigned short*)ws; ws += (size_t)N * N_DIN * sizeof(unsigned short);
    unsigned short* wsrc_bf = (unsigned short*)ws; ws += (size_t)N_COUT * N_DIN * sizeof(unsigned short);
    unsigned short* wdst_bf = (unsigned short*)ws; ws += (size_t)N_COUT * N_DIN * sizeof(unsigned short);
    unsigned short* fsrc_bf = (unsigned short*)ws; ws += (size_t)N * N_COUT * sizeof(unsigned short);
    unsigned short* fdst_bf = (unsigned short*)ws; ws += (size_t)N * N_COUT * sizeof(unsigned short);
    int* offsets = (int*)ws;  ws += (size_t)(N + 1) * sizeof(int);
    int* cursor  = (int*)ws;  ws += (size_t)N * sizeof(int);
    int* ssrc    = (int*)ws;  ws += (size_t)E * sizeof(int);

    // 1) convert feat/W to bf16
    convert_all<<<6314, 256, 0, stream>>>(feat, Wsrc, Wdst, feat_bf, wsrc_bf, wdst_bf);

    // 2) bf16 MFMA projections (single pass over feat, 8 waves/block)
    proj_mfma<<<(N + 63) / 64, 512, 0, stream>>>(feat_bf, wsrc_bf, bsrc, wdst_bf, bdst,
                                                 fsrc_bf, fdst_bf, N);

    // 3) CSR by dst
    zero_ints<<<(N + 255) / 256, 256, 0, stream>>>(cursor, N);
    count_deg<<<(E + 255) / 256, 256, 0, stream>>>(dst, cursor, E);
    scan_kernel<<<1, 1024, 0, stream>>>(cursor, offsets, cursor, N);
    scatter_edges<<<(E + 255) / 256, 256, 0, stream>>>(src, dst, cursor, ssrc, E);

    // 4) fused edge softmax + aggregation
    gat_node2<<<(N + 3) / 4, 256, 0, stream>>>(fsrc_bf, fdst_bf, attn, offsets, ssrc, out, N);
}

// Round 4
// 257.669 us; speedup vs baseline: 2.2387x; 1.1978x over previous
//
#include <hip/hip_runtime.h>
#include <hip/hip_bf16.h>
#include <math.h>

#define N_DIN 256      // D_IN
#define N_COUT 256     // H*D_OUT
#define NEG_SLOPE 0.2f

typedef short s16x8 __attribute__((ext_vector_type(8)));
typedef float f32x4 __attribute__((ext_vector_type(4)));

__device__ __forceinline__ float bf2f(unsigned short u) {
    return __uint_as_float(((unsigned int)u) << 16);
}
__device__ __forceinline__ unsigned short f2bf(float f) {
    __hip_bfloat16 h = __float2bfloat16(f);
    return *reinterpret_cast<unsigned short*>(&h);
}
__device__ __forceinline__ float lrelu(float x) {
    return fmaxf(x, 0.f) + NEG_SLOPE * fminf(x, 0.f);
}

// ---------------- fp32 -> bf16 conversion (feat, Wsrc, Wdst) + cursor zeroing ----------------
// grid: [0,6250) feat, [6250,6282) Wsrc, [6282,6314) Wdst, [6314,6314+196) zero cursor
__global__ __launch_bounds__(256) void convert_all(
    const float* __restrict__ feat, const float* __restrict__ Wsrc,
    const float* __restrict__ Wdst, unsigned short* __restrict__ feat_bf,
    unsigned short* __restrict__ wsrc_bf, unsigned short* __restrict__ wdst_bf,
    int* __restrict__ cursor, int n)
{
    const int b = blockIdx.x;
    if (b >= 6314) {
        int i = (b - 6314) * 256 + threadIdx.x;
        if (i < n) cursor[i] = 0;
        return;
    }
    const float* __restrict__ in;
    unsigned short* __restrict__ out;
    size_t base;
    if (b < 6250)      { in = feat; out = feat_bf; base = (size_t)b * 2048; }
    else if (b < 6282) { in = Wsrc; out = wsrc_bf; base = (size_t)(b - 6250) * 2048; }
    else               { in = Wdst; out = wdst_bf; base = (size_t)(b - 6282) * 2048; }
    size_t i = base + (size_t)threadIdx.x * 8;
    float4 v0 = *reinterpret_cast<const float4*>(&in[i]);
    float4 v1 = *reinterpret_cast<const float4*>(&in[i + 4]);
    ushort4 o0 = make_ushort4(f2bf(v0.x), f2bf(v0.y), f2bf(v0.z), f2bf(v0.w));
    ushort4 o1 = make_ushort4(f2bf(v1.x), f2bf(v1.y), f2bf(v1.z), f2bf(v1.w));
    *reinterpret_cast<ushort4*>(&out[i]) = o0;
    *reinterpret_cast<ushort4*>(&out[i + 4]) = o1;
}

// ---------------- bf16 MFMA projection (unchanged from round 3) ----------------
__global__ __launch_bounds__(512) void proj_mfma(
    const unsigned short* __restrict__ feat_bf,
    const unsigned short* __restrict__ wsrc_bf, const float* __restrict__ bsrc,
    const unsigned short* __restrict__ wdst_bf, const float* __restrict__ bdst,
    unsigned short* __restrict__ fsrc_bf, unsigned short* __restrict__ fdst_bf, int n)
{
    const int t = threadIdx.x;
    const int lane = t & 63;
    const int w = t >> 6;
    const unsigned short* __restrict__ W = (w < 4) ? wsrc_bf : wdst_bf;
    const float* __restrict__ bias       = (w < 4) ? bsrc : bdst;
    unsigned short* __restrict__ outp    = (w < 4) ? fsrc_bf : fdst_bf;
    const int col0 = (w & 3) * 64;
    const int row0 = blockIdx.x * 64;

    const int lr = lane & 15;
    const int kc = lane >> 4;    // k-chunk (8 bf16 each)

    int brow[4];
    #pragma unroll
    for (int m = 0; m < 4; ++m) {
        int r = row0 + m * 16 + lr;
        brow[m] = (r < n) ? r : (n - 1);
    }

    f32x4 acc[4][4] = {};   // [nf][m]

    #pragma unroll
    for (int k0 = 0; k0 < N_DIN; k0 += 32) {
        s16x8 a[4], b[4];
        #pragma unroll
        for (int nf = 0; nf < 4; ++nf)
            a[nf] = *reinterpret_cast<const s16x8*>(
                &W[(size_t)(col0 + nf * 16 + lr) * N_DIN + k0 + kc * 8]);
        #pragma unroll
        for (int m = 0; m < 4; ++m)
            b[m] = *reinterpret_cast<const s16x8*>(
                &feat_bf[(size_t)brow[m] * N_DIN + k0 + kc * 8]);
        #pragma unroll
        for (int nf = 0; nf < 4; ++nf)
            #pragma unroll
            for (int m = 0; m < 4; ++m)
                acc[nf][m] = __builtin_amdgcn_mfma_f32_16x16x32_bf16(
                    a[nf], b[m], acc[nf][m], 0, 0, 0);
    }

    #pragma unroll
    for (int nf = 0; nf < 4; ++nf) {
        const int cbase = col0 + nf * 16 + kc * 4;
        const float4 bv = *reinterpret_cast<const float4*>(&bias[cbase]);
        #pragma unroll
        for (int m = 0; m < 4; ++m) {
            const int row = row0 + m * 16 + lr;
            if (row < n) {
                ushort4 o = make_ushort4(f2bf(acc[nf][m][0] + bv.x),
                                         f2bf(acc[nf][m][1] + bv.y),
                                         f2bf(acc[nf][m][2] + bv.z),
                                         f2bf(acc[nf][m][3] + bv.w));
                *reinterpret_cast<ushort4*>(&outp[(size_t)row * N_COUT + cbase]) = o;
            }
        }
    }
}

// ---------------- CSR build ----------------
__global__ void count_deg(const int* __restrict__ dst, int* __restrict__ deg, int E)
{
    int i = blockIdx.x * 256 + threadIdx.x;
    if (i < E) atomicAdd(&deg[dst[i]], 1);
}

// phase 1: per-block (1024-wide) exclusive scan; partial into offsets, totals into bsum
__global__ __launch_bounds__(1024) void scan_part(
    const int* __restrict__ deg, int* __restrict__ offsets, int* __restrict__ bsum, int n)
{
    __shared__ int wsum[16];
    const int t = threadIdx.x, lane = t & 63, wv = t >> 6;
    const int i = blockIdx.x * 1024 + t;
    int v = (i < n) ? deg[i] : 0;
    int x = v;
    #pragma unroll
    for (int o = 1; o < 64; o <<= 1) {
        int y = __shfl_up(x, (unsigned)o);
        if (lane >= o) x += y;
    }
    if (lane == 63) wsum[wv] = x;
    __syncthreads();
    if (t < 16) {
        int s = wsum[t];
        #pragma unroll
        for (int o = 1; o < 16; o <<= 1) {
            int y = __shfl_up(s, (unsigned)o);
            if (t >= o) s += y;
        }
        wsum[t] = s;
    }
    __syncthreads();
    int wbase = wv ? wsum[wv - 1] : 0;
    if (i < n) offsets[i] = wbase + x - v;
    if (t == 0) bsum[blockIdx.x] = wsum[15];
}

// phase 2: one wave scans the <=64 block sums (exclusive, in place); total -> offsets[n]
__global__ __launch_bounds__(64) void scan_mid(
    int* __restrict__ bsum, int* __restrict__ offsets, int nb, int n)
{
    const int lane = threadIdx.x;
    int v = (lane < nb) ? bsum[lane] : 0;
    int x = v;
    #pragma unroll
    for (int o = 1; o < 64; o <<= 1) {
        int y = __shfl_up(x, (unsigned)o);
        if (lane >= o) x += y;
    }
    if (lane < nb) bsum[lane] = x - v;
    if (lane == 63) offsets[n] = x;
}

// phase 3: add block base; also materialize cursor
__global__ __launch_bounds__(1024) void scan_add(
    const int* __restrict__ bsum, int* __restrict__ offsets, int* __restrict__ cursor, int n)
{
    int i = blockIdx.x * 1024 + threadIdx.x;
    if (i < n) {
        int o = offsets[i] + bsum[blockIdx.x];
        offsets[i] = o;
        cursor[i] = o;
    }
}

__global__ void scatter_edges(const int* __restrict__ src, const int* __restrict__ dst,
                              int* __restrict__ cursor, int* __restrict__ ssrc, int E)
{
    int i = blockIdx.x * 256 + threadIdx.x;
    if (i < E) {
        int d = dst[i];
        int pos = atomicAdd(&cursor[d], 1);
        ssrc[pos] = src[i];
    }
}

// ---------------- fused per-dst-node pass: wave-per-node, 4-edge unroll + defer-max ----------------
__global__ __launch_bounds__(256) void gat_node4(
    const unsigned short* __restrict__ fsrc_bf, const unsigned short* __restrict__ fdst_bf,
    const float* __restrict__ attn, const int* __restrict__ offsets,
    const int* __restrict__ ssrc, float* __restrict__ out, int n)
{
    const int v = blockIdx.x * 4 + (threadIdx.x >> 6);
    if (v >= n) return;
    const int lane = threadIdx.x & 63;
    const int cb = lane * 4;

    ushort4 fdr = *reinterpret_cast<const ushort4*>(&fdst_bf[(size_t)v * N_COUT + cb]);
    const float fd0 = bf2f(fdr.x), fd1 = bf2f(fdr.y), fd2 = bf2f(fdr.z), fd3 = bf2f(fdr.w);
    const float4 aw = *reinterpret_cast<const float4*>(&attn[cb]);

    const int beg = offsets[v];
    const int end = offsets[v + 1];

    float m = -INFINITY, l = 0.f;
    float acc0 = 0.f, acc1 = 0.f, acc2 = 0.f, acc3 = 0.f;

    int j = beg;
    for (; j + 4 <= end; j += 4) {
        float f[4][4], s[4];
        #pragma unroll
        for (int q = 0; q < 4; ++q) {
            int u = ssrc[j + q];
            ushort4 fr = *reinterpret_cast<const ushort4*>(&fsrc_bf[(size_t)u * N_COUT + cb]);
            f[q][0] = bf2f(fr.x); f[q][1] = bf2f(fr.y);
            f[q][2] = bf2f(fr.z); f[q][3] = bf2f(fr.w);
            s[q] = lrelu(f[q][0] + fd0) * aw.x + lrelu(f[q][1] + fd1) * aw.y
                 + lrelu(f[q][2] + fd2) * aw.z + lrelu(f[q][3] + fd3) * aw.w;
        }
        #pragma unroll
        for (int o = 1; o < 16; o <<= 1) {
            s[0] += __shfl_xor(s[0], o);
            s[1] += __shfl_xor(s[1], o);
            s[2] += __shfl_xor(s[2], o);
            s[3] += __shfl_xor(s[3], o);
        }
        float mx = fmaxf(fmaxf(s[0], s[1]), fmaxf(s[2], s[3]));
        if (__all(mx <= m)) {
            // fast path: running max unchanged, no rescale
            float p0 = __expf(s[0] - m), p1 = __expf(s[1] - m);
            float p2 = __expf(s[2] - m), p3 = __expf(s[3] - m);
            l += (p0 + p1) + (p2 + p3);
            acc0 += fmaf(p0, f[0][0], p1 * f[1][0]) + fmaf(p2, f[2][0], p3 * f[3][0]);
            acc1 += fmaf(p0, f[0][1], p1 * f[1][1]) + fmaf(p2, f[2][1], p3 * f[3][1]);
            acc2 += fmaf(p0, f[0][2], p1 * f[1][2]) + fmaf(p2, f[2][2], p3 * f[3][2]);
            acc3 += fmaf(p0, f[0][3], p1 * f[1][3]) + fmaf(p2, f[2][3], p3 * f[3][3]);
        } else {
            float mnew = fmaxf(m, mx);
            float scale = __expf(m - mnew);
            float p0 = __expf(s[0] - mnew), p1 = __expf(s[1] - mnew);
            float p2 = __expf(s[2] - mnew), p3 = __expf(s[3] - mnew);
            l = fmaf(l, scale, (p0 + p1) + (p2 + p3));
            acc0 = fmaf(acc0, scale, fmaf(p0, f[0][0], p1 * f[1][0]) + fmaf(p2, f[2][0], p3 * f[3][0]));
            acc1 = fmaf(acc1, scale, fmaf(p0, f[0][1], p1 * f[1][1]) + fmaf(p2, f[2][1], p3 * f[3][1]));
            acc2 = fmaf(acc2, scale, fmaf(p0, f[0][2], p1 * f[1][2]) + fmaf(p2, f[2][2], p3 * f[3][2]));
            acc3 = fmaf(acc3, scale, fmaf(p0, f[0][3], p1 * f[1][3]) + fmaf(p2, f[2][3], p3 * f[3][3]));
            m = mnew;
        }
    }
    for (; j < end; ++j) {
        int u = ssrc[j];
        ushort4 fa = *reinterpret_cast<const ushort4*>(&fsrc_bf[(size_t)u * N_COUT + cb]);
        float a0 = bf2f(fa.x), a1 = bf2f(fa.y), a2 = bf2f(fa.z), a3 = bf2f(fa.w);
        float sa = lrelu(a0 + fd0) * aw.x + lrelu(a1 + fd1) * aw.y
                 + lrelu(a2 + fd2) * aw.z + lrelu(a3 + fd3) * aw.w;
        sa += __shfl_xor(sa, 1);
        sa += __shfl_xor(sa, 2);
        sa += __shfl_xor(sa, 4);
        sa += __shfl_xor(sa, 8);
        float mnew = fmaxf(m, sa);
        float scale = __expf(m - mnew);
        float pa = __expf(sa - mnew);
        l = fmaf(l, scale, pa);
        acc0 = fmaf(acc0, scale, pa * a0);
        acc1 = fmaf(acc1, scale, pa * a1);
        acc2 = fmaf(acc2, scale, pa * a2);
        acc3 = fmaf(acc3, scale, pa * a3);
        m = mnew;
    }

    const float inv = (l > 0.f) ? (1.0f / l) : 0.f;
    float4 o = make_float4(acc0 * inv, acc1 * inv, acc2 * inv, acc3 * inv);
    *reinterpret_cast<float4*>(&out[(size_t)v * N_COUT + cb]) = o;
}

// ---------------- launch ----------------
extern "C" void kernel_launch(void* const* d_in, const int* in_sizes, int n_in,
                              void* d_out, int out_size, void* d_ws, size_t ws_size,
                              hipStream_t stream)
{
    const float* feat = (const float*)d_in[0];
    const int*   src  = (const int*)d_in[1];
    const int*   dst  = (const int*)d_in[2];
    const float* Wsrc = (const float*)d_in[3];
    const float* bsrc = (const float*)d_in[4];
    const float* Wdst = (const float*)d_in[5];
    const float* bdst = (const float*)d_in[6];
    const float* attn = (const float*)d_in[7];

    const int N = in_sizes[0] / N_DIN;     // 50000
    const int E = in_sizes[1];             // 800000
    float* out = (float*)d_out;

    // workspace layout (all 16B-aligned)
    char* ws = (char*)d_ws;
    unsigned short* feat_bf = (unsigned short*)ws; ws += (size_t)N * N_DIN * sizeof(unsigned short);
    unsigned short* wsrc_bf = (unsigned short*)ws; ws += (size_t)N_COUT * N_DIN * sizeof(unsigned short);
    unsigned short* wdst_bf = (unsigned short*)ws; ws += (size_t)N_COUT * N_DIN * sizeof(unsigned short);
    unsigned short* fsrc_bf = (unsigned short*)ws; ws += (size_t)N * N_COUT * sizeof(unsigned short);
    unsigned short* fdst_bf = (unsigned short*)ws; ws += (size_t)N * N_COUT * sizeof(unsigned short);
    int* offsets = (int*)ws;  ws += (size_t)(N + 64) * sizeof(int);
    int* cursor  = (int*)ws;  ws += (size_t)N * sizeof(int);
    int* bsum    = (int*)ws;  ws += 64 * sizeof(int);
    int* ssrc    = (int*)ws;  ws += (size_t)E * sizeof(int);

    const int nscan = (N + 1023) / 1024;   // 49

    // 1) convert feat/W to bf16 + zero cursor (merged)
    convert_all<<<6314 + (N + 255) / 256, 256, 0, stream>>>(
        feat, Wsrc, Wdst, feat_bf, wsrc_bf, wdst_bf, cursor, N);

    // 2) bf16 MFMA projections
    proj_mfma<<<(N + 63) / 64, 512, 0, stream>>>(feat_bf, wsrc_bf, bsrc, wdst_bf, bdst,
                                                 fsrc_bf, fdst_bf, N);

    // 3) CSR by dst (parallel 3-phase scan)
    count_deg<<<(E + 255) / 256, 256, 0, stream>>>(dst, cursor, E);
    scan_part<<<nscan, 1024, 0, stream>>>(cursor, offsets, bsum, N);
    scan_mid<<<1, 64, 0, stream>>>(bsum, offsets, nscan, N);
    scan_add<<<nscan, 1024, 0, stream>>>(bsum, offsets, cursor, N);
    scatter_edges<<<(E + 255) / 256, 256, 0, stream>>>(src, dst, cursor, ssrc, E);

    // 4) fused edge softmax + aggregation
    gat_node4<<<(N + 3) / 4, 256, 0, stream>>>(fsrc_bf, fdst_bf, attn, offsets, ssrc, out, N);
}